// Round 15
// baseline (191.485 us; speedup 1.0000x reference)
//
#include <hip/hip_runtime.h>
#include <hip/hip_bf16.h>

typedef __hip_bfloat16 bf16;

#define B_   2
#define L_   1024
#define DM_  512
#define DI_  1024
#define N_   16
#define K_   12
#define DTR_ 32

static constexpr int BLD  = B_ * L_ * DI_;   // 2097152
static constexpr int BL   = B_ * L_;         // 2048

using bf16x8 = __attribute__((ext_vector_type(8))) short;
using f32x4  = __attribute__((ext_vector_type(4))) float;
using u16x8  = __attribute__((ext_vector_type(8))) unsigned short;

__device__ __forceinline__ float siluf(float x) { return x / (1.f + __expf(-x)); }
__device__ __forceinline__ float softplusf(float x) {
    return fmaxf(x, 0.f) + log1pf(expf(-fabsf(x)));
}
__device__ __forceinline__ float seluf(float x) {
    const float lam = 1.0507009873554805f, alp = 1.6732632423543772f;
    return x > 0.f ? lam * x : lam * alp * (expf(x) - 1.f);
}
__device__ __forceinline__ ushort bfbits(float x) {
    bf16 v = __float2bfloat16(x);
    return *(ushort*)&v;
}
__device__ __forceinline__ float bf2f(ushort u) {
    return __uint_as_float(((unsigned)u) << 16);
}
// native hardware exp2 (single v_exp_f32); fallback keeps correctness
__device__ __forceinline__ float fexp2(float x) {
#if __has_builtin(__builtin_amdgcn_exp2f)
    return __builtin_amdgcn_exp2f(x);
#else
    return __expf(x * 0.6931471805599453f);
#endif
}

// ---------------- weight cast f32 -> bf16 (6 segments, vec4) ----------------
__global__ __launch_bounds__(256) void cast_w(
    const float* __restrict__ s0, const float* __restrict__ s1, const float* __restrict__ s2,
    const float* __restrict__ s3, const float* __restrict__ s4, const float* __restrict__ s5,
    bf16* __restrict__ dst)
{
    int i = blockIdx.x * 256 + threadIdx.x;   // total 942080 vec4
    const float* src; int off;
    if (i < 262144)      { src = s0; off = i; }
    else if (i < 278528) { src = s1; off = i - 262144; }
    else if (i < 286720) { src = s2; off = i - 278528; }
    else if (i < 417792) { src = s3; off = i - 286720; }
    else if (i < 679936) { src = s4; off = i - 417792; }
    else                 { src = s5; off = i - 679936; }
    float4 v = ((const float4*)src)[off];
    bf16* d = dst + (size_t)i * 4;
    d[0] = __float2bfloat16(v.x); d[1] = __float2bfloat16(v.y);
    d[2] = __float2bfloat16(v.z); d[3] = __float2bfloat16(v.w);
}

// ---------------- LayerNorm: one wave per row of 512, bf16 out ----------------
__global__ __launch_bounds__(256) void ln_kernel(
    const float* __restrict__ x, const float* __restrict__ w, const float* __restrict__ b,
    const float* __restrict__ mask, bf16* __restrict__ y)
{
    int row  = blockIdx.x * 4 + (threadIdx.x >> 6);
    int lane = threadIdx.x & 63;
    const float* xr = x + (size_t)row * DM_;
    float mval = mask ? mask[row] : 1.0f;
    float v[8];
    float s = 0.f, ss = 0.f;
#pragma unroll
    for (int i = 0; i < 8; i++) {
        v[i] = xr[lane + i * 64] * mval;
        s += v[i]; ss += v[i] * v[i];
    }
#pragma unroll
    for (int o = 32; o >= 1; o >>= 1) { s += __shfl_xor(s, o); ss += __shfl_xor(ss, o); }
    float mean = s * (1.f / DM_);
    float var  = ss * (1.f / DM_) - mean * mean;
    float r    = rsqrtf(var + 1e-5f);
    bf16* yr = y + (size_t)row * DM_;
#pragma unroll
    for (int i = 0; i < 8; i++) {
        int c = lane + i * 64;
        yr[c] = __float2bfloat16((v[i] - mean) * r * w[c] + b[c]);
    }
}

// ---------------- fused: (P0+P1) * mask -> LayerNorm -> bf16 (for mo path) ----------------
__global__ __launch_bounds__(256) void ln2r_kernel(
    const float* __restrict__ P, const float* __restrict__ w, const float* __restrict__ b,
    const float* __restrict__ mask, bf16* __restrict__ y)
{
    int row  = blockIdx.x * 4 + (threadIdx.x >> 6);
    int lane = threadIdx.x & 63;
    const float* p0 = P + (size_t)row * DM_;
    const float* p1 = P + (size_t)BL * DM_ + (size_t)row * DM_;
    float mval = mask[row];
    float v[8];
    float s = 0.f, ss = 0.f;
#pragma unroll
    for (int i = 0; i < 8; i++) {
        int c = lane + i * 64;
        v[i] = (p0[c] + p1[c]) * mval;
        s += v[i]; ss += v[i] * v[i];
    }
#pragma unroll
    for (int o = 32; o >= 1; o >>= 1) { s += __shfl_xor(s, o); ss += __shfl_xor(ss, o); }
    float mean = s * (1.f / DM_);
    float var  = ss * (1.f / DM_) - mean * mean;
    float r    = rsqrtf(var + 1e-5f);
    bf16* yr = y + (size_t)row * DM_;
#pragma unroll
    for (int i = 0; i < 8; i++) {
        int c = lane + i * 64;
        yr[c] = __float2bfloat16((v[i] - mean) * r * w[c] + b[c]);
    }
}

// ---------------- MFMA GEMM: C(M,N) = A(M,K) @ W(N,K)^T  (bf16 in, fp32 acc) ----------------
// KS>1: write fp32 partials at C + z*M*N. KS==1 MODE: 0 plain  1 bias[n]+softplus
// 2 bias[n]+selu  4 bias[m]+softplus. zoffW/zoffC: per-blockIdx.z operand offsets (dir batching).
template<int MODE, int BK, int KS>
__global__ __launch_bounds__(256) void mgemm_k(
    const short* __restrict__ A, int lda,
    const short* __restrict__ W, int ldw,
    float* __restrict__ C, bf16* __restrict__ Cb,
    const float* __restrict__ bias,
    size_t zoffW, size_t zoffC,
    int M, int N, int Kd)
{
    constexpr int SP = BK + 8;                // padded LDS row stride (bf16 elems)
    __shared__ short As[64 * SP];
    __shared__ short Ws[64 * SP];
    W += (size_t)blockIdx.z * zoffW;
    if (C)  C  += (size_t)blockIdx.z * zoffC;
    if (Cb) Cb += (size_t)blockIdx.z * zoffC;
    int bm = blockIdx.y * 64, bn = blockIdx.x * 64;
    int tid = threadIdx.x;
    int lane = tid & 63, w = tid >> 6;
    int wm = (w >> 1) * 32, wn = (w & 1) * 32;
    int l15 = lane & 15, l4 = lane >> 4;
    f32x4 acc[2][2] = {};
    int srow = tid >> 2;
    int scol = (tid & 3) * (BK / 4);
    int kbeg = (KS > 1) ? blockIdx.z * (Kd / KS) : 0;
    int kend = (KS > 1) ? kbeg + Kd / KS : Kd;
    const short* Ap = A + (size_t)(bm + srow) * lda + scol;
    const short* Wp = W + (size_t)(bn + srow) * ldw + scol;
    short* Asw = &As[srow * SP + scol];
    short* Wsw = &Ws[srow * SP + scol];
    for (int k0 = kbeg; k0 < kend; k0 += BK) {
#pragma unroll
        for (int i = 0; i < BK / 32; i++) {
            *(bf16x8*)(Asw + i * 8) = *(const bf16x8*)(Ap + k0 + i * 8);
            *(bf16x8*)(Wsw + i * 8) = *(const bf16x8*)(Wp + k0 + i * 8);
        }
        __syncthreads();
#pragma unroll
        for (int ks = 0; ks < BK / 32; ks++) {
            bf16x8 af[2], bfr[2];
#pragma unroll
            for (int mi = 0; mi < 2; mi++)
                af[mi] = *(const bf16x8*)&As[(wm + mi * 16 + l15) * SP + ks * 32 + l4 * 8];
#pragma unroll
            for (int ni = 0; ni < 2; ni++)
                bfr[ni] = *(const bf16x8*)&Ws[(wn + ni * 16 + l15) * SP + ks * 32 + l4 * 8];
#pragma unroll
            for (int mi = 0; mi < 2; mi++)
#pragma unroll
                for (int ni = 0; ni < 2; ni++)
                    acc[mi][ni] = __builtin_amdgcn_mfma_f32_16x16x32_bf16(af[mi], bfr[ni], acc[mi][ni], 0, 0, 0);
        }
        __syncthreads();
    }
    if (KS > 1) {
        float* P = C + (size_t)blockIdx.z * M * N;
#pragma unroll
        for (int mi = 0; mi < 2; mi++) {
            int row0 = bm + wm + mi * 16 + l4 * 4;
#pragma unroll
            for (int ni = 0; ni < 2; ni++) {
                int col = bn + wn + ni * 16 + l15;
#pragma unroll
                for (int j = 0; j < 4; j++)
                    P[(size_t)(row0 + j) * N + col] = acc[mi][ni][j];
            }
        }
    } else {
#pragma unroll
        for (int mi = 0; mi < 2; mi++) {
            int row0 = bm + wm + mi * 16 + l4 * 4;
#pragma unroll
            for (int ni = 0; ni < 2; ni++) {
                int col = bn + wn + ni * 16 + l15;
#pragma unroll
                for (int j = 0; j < 4; j++) {
                    int row = row0 + j;
                    float v = acc[mi][ni][j];
                    if (MODE == 1) v = softplusf(v + bias[col]);
                    if (MODE == 2) v = seluf(v + bias[col]);
                    if (MODE == 4) v = softplusf(v + bias[row]);
                    if (C)  C[(size_t)row * N + col] = v;
                    if (Cb) Cb[(size_t)row * N + col] = __float2bfloat16(v);
                }
            }
        }
    }
}

// ---------------- split-K reduce: sum KS partial slices (+ optional bias/resid) ----------------
template<int KS, int RMODE>
__global__ __launch_bounds__(256) void reduce_k(
    const float* __restrict__ P, float* __restrict__ C, bf16* __restrict__ Cb,
    const float* __restrict__ bias, const float* __restrict__ resid,
    int MN, int N)
{
    int i = (blockIdx.x * 256 + threadIdx.x) * 4;
    float4 v = *(const float4*)(P + i);
#pragma unroll
    for (int s = 1; s < KS; s++) {
        float4 u = *(const float4*)(P + (size_t)s * MN + i);
        v.x += u.x; v.y += u.y; v.z += u.z; v.w += u.w;
    }
    if (RMODE == 1) {
        float4 bz = *(const float4*)(bias + (i % N));
        float4 rx = *(const float4*)(resid + i);
        v.x += bz.x + rx.x; v.y += bz.y + rx.y;
        v.z += bz.z + rx.z; v.w += bz.w + rx.w;
    }
    if (C) *(float4*)(C + i) = v;
    if (Cb) {
        bf16* d = Cb + i;
        d[0] = __float2bfloat16(v.x); d[1] = __float2bfloat16(v.y);
        d[2] = __float2bfloat16(v.z); d[3] = __float2bfloat16(v.w);
    }
}

// ---------------- depthwise conv + SiLU: 4 ch x 8 pos / thread, dual output (row + transposed) ----------------
__global__ __launch_bounds__(256) void conv_silu_kernel(
    const float* __restrict__ xz, const float* __restrict__ cw,
    const float* __restrict__ cb, bf16* __restrict__ xcb, bf16* __restrict__ xcbT)
{
    int gid = blockIdx.x * 256 + threadIdx.x;     // 131072 total
    int d4  = (gid & 255) * 4;
    int l0  = ((gid >> 8) & 127) * 8;
    int b   = (gid >> 15) & 1;
    int dir = gid >> 16;
    float wv[4][12];
    {
        const float4* cwp = (const float4*)(cw + d4 * 12);
        float buf[48];
#pragma unroll
        for (int i = 0; i < 12; i++) {
            float4 t = cwp[i];
            buf[4*i] = t.x; buf[4*i+1] = t.y; buf[4*i+2] = t.z; buf[4*i+3] = t.w;
        }
#pragma unroll
        for (int dd = 0; dd < 4; dd++)
#pragma unroll
            for (int k = 0; k < 12; k++) wv[dd][k] = buf[dd * 12 + k];
    }
    float4 cb4 = *(const float4*)(cb + d4);
    float4 tap[19];
    int tbase = (dir == 0) ? (l0 - (K_ - 1)) : l0;
#pragma unroll
    for (int i = 0; i < 19; i++) {
        int ls = tbase + i;
        if (ls >= 0 && ls < L_)
            tap[i] = *(const float4*)(xz + ((size_t)(b * L_ + ls)) * (2 * DI_) + d4);
        else
            tap[i] = make_float4(0.f, 0.f, 0.f, 0.f);
    }
    ushort ot[4][8];
#pragma unroll
    for (int j = 0; j < 8; j++) {
        float a0 = cb4.x, a1 = cb4.y, a2 = cb4.z, a3 = cb4.w;
        if (dir == 0) {
#pragma unroll
            for (int k = 0; k < K_; k++) {
                float4 t = tap[j + k];
                a0 = fmaf(wv[0][k], t.x, a0); a1 = fmaf(wv[1][k], t.y, a1);
                a2 = fmaf(wv[2][k], t.z, a2); a3 = fmaf(wv[3][k], t.w, a3);
            }
        } else {
#pragma unroll
            for (int k = 0; k < K_; k++) {
                float4 t = tap[j + (K_ - 1) - k];
                a0 = fmaf(wv[0][k], t.x, a0); a1 = fmaf(wv[1][k], t.y, a1);
                a2 = fmaf(wv[2][k], t.z, a2); a3 = fmaf(wv[3][k], t.w, a3);
            }
        }
        ot[0][j] = bfbits(siluf(a0)); ot[1][j] = bfbits(siluf(a1));
        ot[2][j] = bfbits(siluf(a2)); ot[3][j] = bfbits(siluf(a3));
    }
    // row-major store [bl][d]
    size_t obase = (size_t)dir * BLD + ((size_t)(b * L_ + l0)) * DI_ + d4;
#pragma unroll
    for (int j = 0; j < 8; j++) {
        ushort4 o; o.x = ot[0][j]; o.y = ot[1][j]; o.z = ot[2][j]; o.w = ot[3][j];
        *(ushort4*)(xcb + obase + (size_t)j * DI_) = o;
    }
    // transposed store [d][bl]
#pragma unroll
    for (int dd = 0; dd < 4; dd++) {
        u16x8 v;
#pragma unroll
        for (int j = 0; j < 8; j++) v[j] = ot[dd][j];
        *(u16x8*)(xcbT + ((size_t)dir * DI_ + d4 + dd) * BL + (size_t)b * L_ + l0) = v;
    }
}

// ---------------- chunked selective scan: 1 d per block, 128 thr = 4 ngrp x 32 chunks ----------------
// grid (DI, B, 2 dirs) = 4096 blocks -> 16 blocks/CU x 2 waves = 32 waves/CU (100% occ)
// A pre-scaled by log2(e): a = exp2(dt * A') -> single native v_exp_f32
__global__ __launch_bounds__(128, 8) void scan_kernel(
    const float* __restrict__ dtT,   // [2][DI][BL] f32
    const bf16*  __restrict__ xcT,   // [2][DI][BL] bf16
    const float* __restrict__ dbl,   // [2][BL][64] f32
    const float* __restrict__ A_log, const float* __restrict__ Dp,
    float* __restrict__ y2)          // [2][DI][BL] f32
{
    __shared__ float sA[32][17];
    __shared__ float sB[32][17];
    __shared__ float sY[32][36];
    int d = blockIdx.x, b = blockIdx.y, dir = blockIdx.z;
    int tid = threadIdx.x;
    int ng = tid & 3, c = tid >> 2;
    size_t rowbase = ((size_t)dir * DI_ + d) * BL + (size_t)b * L_;
    const float* dtp = dtT + rowbase;
    const bf16*  xcp = xcT + rowbase;
    const float* dblp = dbl + ((size_t)dir * BL + (size_t)b * L_) * 64;
    int nb = ng * 4;
    const float LOG2E = 1.44269504088896f;
    float A0 = -__expf(A_log[d * N_ + nb + 0]) * LOG2E;
    float A1 = -__expf(A_log[d * N_ + nb + 1]) * LOG2E;
    float A2 = -__expf(A_log[d * N_ + nb + 2]) * LOG2E;
    float A3 = -__expf(A_log[d * N_ + nb + 3]) * LOG2E;
    float Dd = Dp[d];
    int l0 = c * 32;
    // pass 1: local scan -> chunk summaries
    float ac0=1.f, ac1=1.f, ac2=1.f, ac3=1.f;
    float h0=0.f, h1=0.f, h2=0.f, h3=0.f;
    for (int j = 0; j < 32; j += 4) {
        float4 dt4 = *(const float4*)(dtp + l0 + j);
        ushort4 xcu = *(const ushort4*)(xcp + l0 + j);
#pragma unroll
        for (int q = 0; q < 4; q++) {
            int l = l0 + j + q;
            float dtv = ((const float*)&dt4)[q];
            float xcv = bf2f(((const ushort*)&xcu)[q]);
            float4 B4 = *(const float4*)(dblp + (size_t)l * 64 + DTR_ + nb);
            float dx = dtv * xcv;
            float a0 = fexp2(dtv * A0), a1 = fexp2(dtv * A1),
                  a2 = fexp2(dtv * A2), a3 = fexp2(dtv * A3);
            ac0 *= a0; ac1 *= a1; ac2 *= a2; ac3 *= a3;
            h0 = fmaf(a0, h0, dx * B4.x); h1 = fmaf(a1, h1, dx * B4.y);
            h2 = fmaf(a2, h2, dx * B4.z); h3 = fmaf(a3, h3, dx * B4.w);
        }
    }
    sA[c][nb+0]=ac0; sA[c][nb+1]=ac1; sA[c][nb+2]=ac2; sA[c][nb+3]=ac3;
    sB[c][nb+0]=h0;  sB[c][nb+1]=h1;  sB[c][nb+2]=h2;  sB[c][nb+3]=h3;
    __syncthreads();
    // exclusive cross-chunk prefix (<=31 steps, serial per lane)
    float p0=0.f, p1=0.f, p2=0.f, p3=0.f;
    for (int cc = 0; cc < c; cc++) {
        p0 = fmaf(sA[cc][nb+0], p0, sB[cc][nb+0]);
        p1 = fmaf(sA[cc][nb+1], p1, sB[cc][nb+1]);
        p2 = fmaf(sA[cc][nb+2], p2, sB[cc][nb+2]);
        p3 = fmaf(sA[cc][nb+3], p3, sB[cc][nb+3]);
    }
    h0 = p0; h1 = p1; h2 = p2; h3 = p3;
    // pass 2: rescan + n-reduce (in-reg 4 + shfl over ng bits 0..1)
    for (int j = 0; j < 32; j += 4) {
        float4 dt4 = *(const float4*)(dtp + l0 + j);
        ushort4 xcu = *(const ushort4*)(xcp + l0 + j);
#pragma unroll
        for (int q = 0; q < 4; q++) {
            int l = l0 + j + q;
            float dtv = ((const float*)&dt4)[q];
            float xcv = bf2f(((const ushort*)&xcu)[q]);
            float4 B4 = *(const float4*)(dblp + (size_t)l * 64 + DTR_ + nb);
            float4 C4 = *(const float4*)(dblp + (size_t)l * 64 + DTR_ + N_ + nb);
            float dx = dtv * xcv;
            float a0 = fexp2(dtv * A0), a1 = fexp2(dtv * A1),
                  a2 = fexp2(dtv * A2), a3 = fexp2(dtv * A3);
            h0 = fmaf(a0, h0, dx * B4.x); h1 = fmaf(a1, h1, dx * B4.y);
            h2 = fmaf(a2, h2, dx * B4.z); h3 = fmaf(a3, h3, dx * B4.w);
            float p = h0 * C4.x;
            p = fmaf(h1, C4.y, p); p = fmaf(h2, C4.z, p); p = fmaf(h3, C4.w, p);
            p += __shfl_xor(p, 1); p += __shfl_xor(p, 2);
            if (ng == 0) sY[c][j + q] = fmaf(xcv, Dd, p);
        }
    }
    __syncthreads();
    // coalesced write: 1024 floats by 128 threads (8 each, two float4)
    float* yp = y2 + rowbase;
    int base = tid * 8;
    int cw = base >> 5, jw = base & 31;
    *(float4*)(yp + base)     = *(float4*)&sY[cw][jw];
    *(float4*)(yp + base + 4) = *(float4*)&sY[cw][jw + 4];
}

// ---------------- combine + transpose: ycomb_b[bl][d] = (y2_f+y2_b)[d][bl] * silu(z) ----------------
__global__ __launch_bounds__(256) void combine_kernel(
    const float* __restrict__ y2, const float* __restrict__ xz,
    bf16* __restrict__ yc)
{
    __shared__ float tile[32][33];
    int d0 = blockIdx.x * 32, bl0 = blockIdx.y * 32;
    int tx = threadIdx.x & 31, ty = threadIdx.x >> 5;
#pragma unroll
    for (int r = 0; r < 4; r++) {
        int d = d0 + ty * 4 + r;
        tile[ty * 4 + r][tx] = y2[(size_t)d * BL + bl0 + tx]
                             + y2[(size_t)(DI_ + d) * BL + bl0 + tx];
    }
    __syncthreads();
#pragma unroll
    for (int r = 0; r < 4; r++) {
        int bl = bl0 + ty * 4 + r;
        float z = xz[(size_t)bl * (2 * DI_) + DI_ + d0 + tx];
        yc[(size_t)bl * DI_ + d0 + tx] = __float2bfloat16(tile[tx][ty * 4 + r] * siluf(z));
    }
}

extern "C" void kernel_launch(void* const* d_in, const int* in_sizes, int n_in,
                              void* d_out, int out_size, void* d_ws, size_t ws_size,
                              hipStream_t stream) {
    const float* x     = (const float*)d_in[0];
    const float* mask  = (const float*)d_in[1];
    const float* n1w   = (const float*)d_in[2];
    const float* n1b   = (const float*)d_in[3];
    const float* n2w   = (const float*)d_in[4];
    const float* n2b   = (const float*)d_in[5];
    const float* ff1w  = (const float*)d_in[6];
    const float* ff1b  = (const float*)d_in[7];
    const float* ff2w  = (const float*)d_in[8];
    const float* ff2b  = (const float*)d_in[9];
    const float* inpw  = (const float*)d_in[10];
    const float* convw = (const float*)d_in[11];
    const float* convb = (const float*)d_in[12];
    const float* xpw   = (const float*)d_in[13];
    const float* dtpw  = (const float*)d_in[14];
    const float *A_log, *Dp, *outpw, *dtpb;
    if (in_sizes[15] == DI_ * N_) {
        A_log = (const float*)d_in[15]; Dp = (const float*)d_in[16];
        outpw = (const float*)d_in[17]; dtpb = (const float*)d_in[18];
    } else {
        dtpb = (const float*)d_in[15]; A_log = (const float*)d_in[16];
        Dp = (const float*)d_in[17]; outpw = (const float*)d_in[18];
    }

    float* ws = (float*)d_ws;
    bf16*  wb      = (bf16*)ws;                         // 1884160 fu
    float* xz      = ws + 1884160;                      // 4194304 fu (also P9/P12)
    bf16*  xn_b    = (bf16*)(ws + 6078464);             // 524288 fu (also mon_b)
    bf16*  xc_b    = (bf16*)(ws + 6602752);             // 2097152 fu (also h_b)
    float* y2      = ws + 8699904;                      // 4194304 fu  [2][DI][BL]
    float* dblb    = ws + 12894208;                     // 262144 fu
    bf16*  dbl_b   = (bf16*)(ws + 13156352);            // 131072 fu
    float* dtT     = ws + 13287424;                     // 4194304 fu (also P5)
    bf16*  xcT_b   = (bf16*)(ws + 17481728);            // 2097152 fu [2][DI][BL] bf16
    bf16*  ycomb_b = (bf16*)(ws + 19578880);            // 524288 fu

    bf16* inpw_b = wb;
    bf16* xpw_b  = wb + 1048576;
    bf16* dtpw_b = wb + 1114112;
    bf16* outpw_b= wb + 1146880;
    bf16* ff1w_b = wb + 1671168;
    bf16* ff2w_b = wb + 2719744;
    bf16* mon_b  = xn_b;
    bf16* h_b    = xc_b;
    float* P5    = dtT;
    float* P9    = xz;
    float* P12   = xz;

    // 0. cast weights to bf16
    cast_w<<<dim3(3680), 256, 0, stream>>>(inpw, xpw, dtpw, outpw, ff1w, ff2w, wb);
    // 1. xn = LN(x) -> bf16
    ln_kernel<<<dim3(BL / 4), 256, 0, stream>>>(x, n1w, n1b, nullptr, xn_b);
    // 2. xz = xn @ in_proj_w^T (2048x2048x512), grid 1024
    mgemm_k<0, 64, 1><<<dim3(32, 32), 256, 0, stream>>>(
        (const short*)xn_b, DM_, (const short*)inpw_b, DM_, xz, nullptr,
        nullptr, 0, 0, BL, 2 * DI_, DM_);
    // 3. conv + silu -> xc_b [bl][d] AND xcT_b [d][bl]
    conv_silu_kernel<<<dim3(512), 256, 0, stream>>>(xz, convw, convb, xc_b, xcT_b);
    // 4. dbl = xc @ x_proj_w^T (4096x64x1024), split-K 8, grid 512
    mgemm_k<0, 64, 8><<<dim3(1, 64, 8), 256, 0, stream>>>(
        (const short*)xc_b, DI_, (const short*)xpw_b, DI_, P5, nullptr,
        nullptr, 0, 0, 2 * BL, 64, DI_);
    reduce_k<8, 0><<<dim3(256), 256, 0, stream>>>(P5, dblb, dbl_b, nullptr, nullptr,
                                                  2 * BL * 64, 64);
    // 5. dtT = softplus(dt_proj_w @ dt_r^T + b[m]) -> f32 [2][DI][BL], one launch
    mgemm_k<4, 32, 1><<<dim3(32, 16, 2), 256, 0, stream>>>(
        (const short*)dtpw_b, DTR_, (const short*)dbl_b, 64,
        dtT, nullptr, dtpb,
        (size_t)BL * 64, (size_t)DI_ * BL, DI_, BL, DTR_);
    // 6. chunked scan (both dirs, 4096 blocks x 128 thr) -> y2[2][DI][BL]
    scan_kernel<<<dim3(DI_, B_, 2), 128, 0, stream>>>(dtT, xcT_b, dblb, A_log, Dp, y2);
    // 7. ycomb_b = (y2_f + y2_b)^T * silu(z) -> bf16
    combine_kernel<<<dim3(DI_ / 32, BL / 32), 256, 0, stream>>>(y2, xz, ycomb_b);
    // 8. mo_raw partials = ycomb @ out_proj_w^T (2048x512x1024), split-K 2, grid 512
    mgemm_k<0, 64, 2><<<dim3(8, 32, 2), 256, 0, stream>>>(
        (const short*)ycomb_b, DI_, (const short*)outpw_b, DI_, P9, nullptr,
        nullptr, 0, 0, BL, DM_, DI_);
    // 9. mo_n = LN((P9_0 + P9_1) * mask) -> bf16  (fused reduce + LN)
    ln2r_kernel<<<dim3(BL / 4), 256, 0, stream>>>(P9, n2w, n2b, mask, mon_b);
    // 10. h = selu(mo_n @ ff1_w^T + b) -> bf16 (2048x2048x512), grid 1024
    mgemm_k<2, 64, 1><<<dim3(32, 32), 256, 0, stream>>>(
        (const short*)mon_b, DM_, (const short*)ff1w_b, DM_, nullptr, h_b,
        ff1b, 0, 0, BL, 4 * DM_, DM_);
    // 11. out = h @ ff2_w^T (2048x512x2048), split-K 2, grid 512; reduce adds bias + x
    mgemm_k<0, 64, 2><<<dim3(8, 32, 2), 256, 0, stream>>>(
        (const short*)h_b, 4 * DM_, (const short*)ff2w_b, 4 * DM_, P12, nullptr,
        nullptr, 0, 0, BL, DM_, 4 * DM_);
    reduce_k<2, 1><<<dim3(1024), 256, 0, stream>>>(P12, (float*)d_out, nullptr, ff2b, x,
                                                   BL * DM_, DM_);
}

// Round 16
// 184.159 us; speedup vs baseline: 1.0398x; 1.0398x over previous
//
#include <hip/hip_runtime.h>
#include <hip/hip_bf16.h>

typedef __hip_bfloat16 bf16;

#define B_   2
#define L_   1024
#define DM_  512
#define DI_  1024
#define N_   16
#define K_   12
#define DTR_ 32

static constexpr int BLD  = B_ * L_ * DI_;   // 2097152
static constexpr int BL   = B_ * L_;         // 2048

using bf16x8 = __attribute__((ext_vector_type(8))) short;
using f32x4  = __attribute__((ext_vector_type(4))) float;
using u16x8  = __attribute__((ext_vector_type(8))) unsigned short;

__device__ __forceinline__ float siluf(float x) { return x / (1.f + __expf(-x)); }
__device__ __forceinline__ float softplusf(float x) {
    return fmaxf(x, 0.f) + log1pf(expf(-fabsf(x)));
}
__device__ __forceinline__ float seluf(float x) {
    const float lam = 1.0507009873554805f, alp = 1.6732632423543772f;
    return x > 0.f ? lam * x : lam * alp * (expf(x) - 1.f);
}
__device__ __forceinline__ ushort bfbits(float x) {
    bf16 v = __float2bfloat16(x);
    return *(ushort*)&v;
}
__device__ __forceinline__ float bf2f(ushort u) {
    return __uint_as_float(((unsigned)u) << 16);
}
// native hardware exp2 (single v_exp_f32); fallback keeps correctness
__device__ __forceinline__ float fexp2(float x) {
#if __has_builtin(__builtin_amdgcn_exp2f)
    return __builtin_amdgcn_exp2f(x);
#else
    return __expf(x * 0.6931471805599453f);
#endif
}

// ---------------- fused prep: weight cast f32->bf16 (blocks 0..3679) + LN1 (blocks 3680..4191) ----------------
__global__ __launch_bounds__(256) void prep_kernel(
    const float* __restrict__ s0, const float* __restrict__ s1, const float* __restrict__ s2,
    const float* __restrict__ s3, const float* __restrict__ s4, const float* __restrict__ s5,
    bf16* __restrict__ dst,
    const float* __restrict__ x, const float* __restrict__ n1w, const float* __restrict__ n1b,
    bf16* __restrict__ xn)
{
    if (blockIdx.x < 3680) {
        int i = blockIdx.x * 256 + threadIdx.x;   // total 942080 vec4
        const float* src; int off;
        if (i < 262144)      { src = s0; off = i; }
        else if (i < 278528) { src = s1; off = i - 262144; }
        else if (i < 286720) { src = s2; off = i - 278528; }
        else if (i < 417792) { src = s3; off = i - 286720; }
        else if (i < 679936) { src = s4; off = i - 417792; }
        else                 { src = s5; off = i - 679936; }
        float4 v = ((const float4*)src)[off];
        bf16* d = dst + (size_t)i * 4;
        d[0] = __float2bfloat16(v.x); d[1] = __float2bfloat16(v.y);
        d[2] = __float2bfloat16(v.z); d[3] = __float2bfloat16(v.w);
    } else {
        int row  = (blockIdx.x - 3680) * 4 + (threadIdx.x >> 6);
        int lane = threadIdx.x & 63;
        const float* xr = x + (size_t)row * DM_;
        float v[8];
        float s = 0.f, ss = 0.f;
#pragma unroll
        for (int i = 0; i < 8; i++) {
            v[i] = xr[lane + i * 64];
            s += v[i]; ss += v[i] * v[i];
        }
#pragma unroll
        for (int o = 32; o >= 1; o >>= 1) { s += __shfl_xor(s, o); ss += __shfl_xor(ss, o); }
        float mean = s * (1.f / DM_);
        float var  = ss * (1.f / DM_) - mean * mean;
        float r    = rsqrtf(var + 1e-5f);
        bf16* yr = xn + (size_t)row * DM_;
#pragma unroll
        for (int i = 0; i < 8; i++) {
            int c = lane + i * 64;
            yr[c] = __float2bfloat16((v[i] - mean) * r * n1w[c] + n1b[c]);
        }
    }
}

// ---------------- fused: (P0+P1) * mask -> LayerNorm -> bf16 (for mo path) ----------------
__global__ __launch_bounds__(256) void ln2r_kernel(
    const float* __restrict__ P, const float* __restrict__ w, const float* __restrict__ b,
    const float* __restrict__ mask, bf16* __restrict__ y)
{
    int row  = blockIdx.x * 4 + (threadIdx.x >> 6);
    int lane = threadIdx.x & 63;
    const float* p0 = P + (size_t)row * DM_;
    const float* p1 = P + (size_t)BL * DM_ + (size_t)row * DM_;
    float mval = mask[row];
    float v[8];
    float s = 0.f, ss = 0.f;
#pragma unroll
    for (int i = 0; i < 8; i++) {
        int c = lane + i * 64;
        v[i] = (p0[c] + p1[c]) * mval;
        s += v[i]; ss += v[i] * v[i];
    }
#pragma unroll
    for (int o = 32; o >= 1; o >>= 1) { s += __shfl_xor(s, o); ss += __shfl_xor(ss, o); }
    float mean = s * (1.f / DM_);
    float var  = ss * (1.f / DM_) - mean * mean;
    float r    = rsqrtf(var + 1e-5f);
    bf16* yr = y + (size_t)row * DM_;
#pragma unroll
    for (int i = 0; i < 8; i++) {
        int c = lane + i * 64;
        yr[c] = __float2bfloat16((v[i] - mean) * r * w[c] + b[c]);
    }
}

// ---------------- MFMA GEMM: C(M,N) = A(M,K) @ W(N,K)^T  (bf16 in, fp32 acc) ----------------
// KS>1: write fp32 partials at C + z*M*N. KS==1 MODE: 0 plain  1 bias[n]+softplus
// 2 bias[n]+selu  4 bias[m]+softplus. zoffW/zoffC: per-blockIdx.z operand offsets (dir batching).
template<int MODE, int BK, int KS>
__global__ __launch_bounds__(256) void mgemm_k(
    const short* __restrict__ A, int lda,
    const short* __restrict__ W, int ldw,
    float* __restrict__ C, bf16* __restrict__ Cb,
    const float* __restrict__ bias,
    size_t zoffW, size_t zoffC,
    int M, int N, int Kd)
{
    constexpr int SP = BK + 8;                // padded LDS row stride (bf16 elems)
    __shared__ short As[64 * SP];
    __shared__ short Ws[64 * SP];
    W += (size_t)blockIdx.z * zoffW;
    if (C)  C  += (size_t)blockIdx.z * zoffC;
    if (Cb) Cb += (size_t)blockIdx.z * zoffC;
    int bm = blockIdx.y * 64, bn = blockIdx.x * 64;
    int tid = threadIdx.x;
    int lane = tid & 63, w = tid >> 6;
    int wm = (w >> 1) * 32, wn = (w & 1) * 32;
    int l15 = lane & 15, l4 = lane >> 4;
    f32x4 acc[2][2] = {};
    int srow = tid >> 2;
    int scol = (tid & 3) * (BK / 4);
    int kbeg = (KS > 1) ? blockIdx.z * (Kd / KS) : 0;
    int kend = (KS > 1) ? kbeg + Kd / KS : Kd;
    const short* Ap = A + (size_t)(bm + srow) * lda + scol;
    const short* Wp = W + (size_t)(bn + srow) * ldw + scol;
    short* Asw = &As[srow * SP + scol];
    short* Wsw = &Ws[srow * SP + scol];
    for (int k0 = kbeg; k0 < kend; k0 += BK) {
#pragma unroll
        for (int i = 0; i < BK / 32; i++) {
            *(bf16x8*)(Asw + i * 8) = *(const bf16x8*)(Ap + k0 + i * 8);
            *(bf16x8*)(Wsw + i * 8) = *(const bf16x8*)(Wp + k0 + i * 8);
        }
        __syncthreads();
#pragma unroll
        for (int ks = 0; ks < BK / 32; ks++) {
            bf16x8 af[2], bfr[2];
#pragma unroll
            for (int mi = 0; mi < 2; mi++)
                af[mi] = *(const bf16x8*)&As[(wm + mi * 16 + l15) * SP + ks * 32 + l4 * 8];
#pragma unroll
            for (int ni = 0; ni < 2; ni++)
                bfr[ni] = *(const bf16x8*)&Ws[(wn + ni * 16 + l15) * SP + ks * 32 + l4 * 8];
#pragma unroll
            for (int mi = 0; mi < 2; mi++)
#pragma unroll
                for (int ni = 0; ni < 2; ni++)
                    acc[mi][ni] = __builtin_amdgcn_mfma_f32_16x16x32_bf16(af[mi], bfr[ni], acc[mi][ni], 0, 0, 0);
        }
        __syncthreads();
    }
    if (KS > 1) {
        float* P = C + (size_t)blockIdx.z * M * N;
#pragma unroll
        for (int mi = 0; mi < 2; mi++) {
            int row0 = bm + wm + mi * 16 + l4 * 4;
#pragma unroll
            for (int ni = 0; ni < 2; ni++) {
                int col = bn + wn + ni * 16 + l15;
#pragma unroll
                for (int j = 0; j < 4; j++)
                    P[(size_t)(row0 + j) * N + col] = acc[mi][ni][j];
            }
        }
    } else {
#pragma unroll
        for (int mi = 0; mi < 2; mi++) {
            int row0 = bm + wm + mi * 16 + l4 * 4;
#pragma unroll
            for (int ni = 0; ni < 2; ni++) {
                int col = bn + wn + ni * 16 + l15;
#pragma unroll
                for (int j = 0; j < 4; j++) {
                    int row = row0 + j;
                    float v = acc[mi][ni][j];
                    if (MODE == 1) v = softplusf(v + bias[col]);
                    if (MODE == 2) v = seluf(v + bias[col]);
                    if (MODE == 4) v = softplusf(v + bias[row]);
                    if (C)  C[(size_t)row * N + col] = v;
                    if (Cb) Cb[(size_t)row * N + col] = __float2bfloat16(v);
                }
            }
        }
    }
}

// ---------------- split-K reduce: sum KS partial slices (+ optional bias/resid) ----------------
template<int KS, int RMODE>
__global__ __launch_bounds__(256) void reduce_k(
    const float* __restrict__ P, float* __restrict__ C, bf16* __restrict__ Cb,
    const float* __restrict__ bias, const float* __restrict__ resid,
    int MN, int N)
{
    int i = (blockIdx.x * 256 + threadIdx.x) * 4;
    float4 v = *(const float4*)(P + i);
#pragma unroll
    for (int s = 1; s < KS; s++) {
        float4 u = *(const float4*)(P + (size_t)s * MN + i);
        v.x += u.x; v.y += u.y; v.z += u.z; v.w += u.w;
    }
    if (RMODE == 1) {
        float4 bz = *(const float4*)(bias + (i % N));
        float4 rx = *(const float4*)(resid + i);
        v.x += bz.x + rx.x; v.y += bz.y + rx.y;
        v.z += bz.z + rx.z; v.w += bz.w + rx.w;
    }
    if (C) *(float4*)(C + i) = v;
    if (Cb) {
        bf16* d = Cb + i;
        d[0] = __float2bfloat16(v.x); d[1] = __float2bfloat16(v.y);
        d[2] = __float2bfloat16(v.z); d[3] = __float2bfloat16(v.w);
    }
}

// ---------------- depthwise conv + SiLU: 4 ch x 8 pos / thread, dual output (row + transposed) ----------------
__global__ __launch_bounds__(256) void conv_silu_kernel(
    const float* __restrict__ xz, const float* __restrict__ cw,
    const float* __restrict__ cb, bf16* __restrict__ xcb, bf16* __restrict__ xcbT)
{
    int gid = blockIdx.x * 256 + threadIdx.x;     // 131072 total
    int d4  = (gid & 255) * 4;
    int l0  = ((gid >> 8) & 127) * 8;
    int b   = (gid >> 15) & 1;
    int dir = gid >> 16;
    float wv[4][12];
    {
        const float4* cwp = (const float4*)(cw + d4 * 12);
        float buf[48];
#pragma unroll
        for (int i = 0; i < 12; i++) {
            float4 t = cwp[i];
            buf[4*i] = t.x; buf[4*i+1] = t.y; buf[4*i+2] = t.z; buf[4*i+3] = t.w;
        }
#pragma unroll
        for (int dd = 0; dd < 4; dd++)
#pragma unroll
            for (int k = 0; k < 12; k++) wv[dd][k] = buf[dd * 12 + k];
    }
    float4 cb4 = *(const float4*)(cb + d4);
    float4 tap[19];
    int tbase = (dir == 0) ? (l0 - (K_ - 1)) : l0;
#pragma unroll
    for (int i = 0; i < 19; i++) {
        int ls = tbase + i;
        if (ls >= 0 && ls < L_)
            tap[i] = *(const float4*)(xz + ((size_t)(b * L_ + ls)) * (2 * DI_) + d4);
        else
            tap[i] = make_float4(0.f, 0.f, 0.f, 0.f);
    }
    ushort ot[4][8];
#pragma unroll
    for (int j = 0; j < 8; j++) {
        float a0 = cb4.x, a1 = cb4.y, a2 = cb4.z, a3 = cb4.w;
        if (dir == 0) {
#pragma unroll
            for (int k = 0; k < K_; k++) {
                float4 t = tap[j + k];
                a0 = fmaf(wv[0][k], t.x, a0); a1 = fmaf(wv[1][k], t.y, a1);
                a2 = fmaf(wv[2][k], t.z, a2); a3 = fmaf(wv[3][k], t.w, a3);
            }
        } else {
#pragma unroll
            for (int k = 0; k < K_; k++) {
                float4 t = tap[j + (K_ - 1) - k];
                a0 = fmaf(wv[0][k], t.x, a0); a1 = fmaf(wv[1][k], t.y, a1);
                a2 = fmaf(wv[2][k], t.z, a2); a3 = fmaf(wv[3][k], t.w, a3);
            }
        }
        ot[0][j] = bfbits(siluf(a0)); ot[1][j] = bfbits(siluf(a1));
        ot[2][j] = bfbits(siluf(a2)); ot[3][j] = bfbits(siluf(a3));
    }
    // row-major store [bl][d]
    size_t obase = (size_t)dir * BLD + ((size_t)(b * L_ + l0)) * DI_ + d4;
#pragma unroll
    for (int j = 0; j < 8; j++) {
        ushort4 o; o.x = ot[0][j]; o.y = ot[1][j]; o.z = ot[2][j]; o.w = ot[3][j];
        *(ushort4*)(xcb + obase + (size_t)j * DI_) = o;
    }
    // transposed store [d][bl]
#pragma unroll
    for (int dd = 0; dd < 4; dd++) {
        u16x8 v;
#pragma unroll
        for (int j = 0; j < 8; j++) v[j] = ot[dd][j];
        *(u16x8*)(xcbT + ((size_t)dir * DI_ + d4 + dd) * BL + (size_t)b * L_ + l0) = v;
    }
}

// ---------------- chunked selective scan: 32 chunks x 32 steps, 4 n / lane ----------------
// block 256 thr = 32 chunks x 4 ngrp x 2 dloc; grid (DI/2, B, 2 dirs) = 2048 blocks
// A pre-scaled by log2(e): a = exp2(dt * A') -> single native v_exp_f32
__global__ __launch_bounds__(256, 8) void scan_kernel(
    const float* __restrict__ dtT,   // [2][DI][BL] f32
    const bf16*  __restrict__ xcT,   // [2][DI][BL] bf16
    const float* __restrict__ dbl,   // [2][BL][64] f32
    const float* __restrict__ A_log, const float* __restrict__ Dp,
    float* __restrict__ y2)          // [2][DI][BL] f32
{
    __shared__ float sA[32][2][17];
    __shared__ float sB[32][2][17];
    __shared__ float sY[2][32][36];
    int dgrp = blockIdx.x, b = blockIdx.y, dir = blockIdx.z;
    int tid = threadIdx.x;
    int dloc = tid & 1, ng = (tid >> 1) & 3, c = tid >> 3;
    int d = dgrp * 2 + dloc;
    size_t rowbase = ((size_t)dir * DI_ + d) * BL + (size_t)b * L_;
    const float* dtp = dtT + rowbase;
    const bf16*  xcp = xcT + rowbase;
    const float* dblp = dbl + ((size_t)dir * BL + (size_t)b * L_) * 64;
    int nb = ng * 4;
    const float LOG2E = 1.44269504088896f;
    float A0 = -__expf(A_log[d * N_ + nb + 0]) * LOG2E;
    float A1 = -__expf(A_log[d * N_ + nb + 1]) * LOG2E;
    float A2 = -__expf(A_log[d * N_ + nb + 2]) * LOG2E;
    float A3 = -__expf(A_log[d * N_ + nb + 3]) * LOG2E;
    float Dd = Dp[d];
    int l0 = c * 32;
    // pass 1: local scan -> chunk summaries
    float ac0=1.f, ac1=1.f, ac2=1.f, ac3=1.f;
    float h0=0.f, h1=0.f, h2=0.f, h3=0.f;
    for (int j = 0; j < 32; j += 4) {
        float4 dt4 = *(const float4*)(dtp + l0 + j);
        ushort4 xcu = *(const ushort4*)(xcp + l0 + j);
#pragma unroll
        for (int q = 0; q < 4; q++) {
            int l = l0 + j + q;
            float dtv = ((const float*)&dt4)[q];
            float xcv = bf2f(((const ushort*)&xcu)[q]);
            float4 B4 = *(const float4*)(dblp + (size_t)l * 64 + DTR_ + nb);
            float dx = dtv * xcv;
            float a0 = fexp2(dtv * A0), a1 = fexp2(dtv * A1),
                  a2 = fexp2(dtv * A2), a3 = fexp2(dtv * A3);
            ac0 *= a0; ac1 *= a1; ac2 *= a2; ac3 *= a3;
            h0 = fmaf(a0, h0, dx * B4.x); h1 = fmaf(a1, h1, dx * B4.y);
            h2 = fmaf(a2, h2, dx * B4.z); h3 = fmaf(a3, h3, dx * B4.w);
        }
    }
    sA[c][dloc][nb+0]=ac0; sA[c][dloc][nb+1]=ac1; sA[c][dloc][nb+2]=ac2; sA[c][dloc][nb+3]=ac3;
    sB[c][dloc][nb+0]=h0;  sB[c][dloc][nb+1]=h1;  sB[c][dloc][nb+2]=h2;  sB[c][dloc][nb+3]=h3;
    __syncthreads();
    // exclusive cross-chunk prefix (<=31 steps)
    float p0=0.f, p1=0.f, p2=0.f, p3=0.f;
    for (int cc = 0; cc < c; cc++) {
        p0 = fmaf(sA[cc][dloc][nb+0], p0, sB[cc][dloc][nb+0]);
        p1 = fmaf(sA[cc][dloc][nb+1], p1, sB[cc][dloc][nb+1]);
        p2 = fmaf(sA[cc][dloc][nb+2], p2, sB[cc][dloc][nb+2]);
        p3 = fmaf(sA[cc][dloc][nb+3], p3, sB[cc][dloc][nb+3]);
    }
    h0 = p0; h1 = p1; h2 = p2; h3 = p3;
    // pass 2: rescan + n-reduce (in-reg 4 + shfl over ng bits 1..2)
    for (int j = 0; j < 32; j += 4) {
        float4 dt4 = *(const float4*)(dtp + l0 + j);
        ushort4 xcu = *(const ushort4*)(xcp + l0 + j);
#pragma unroll
        for (int q = 0; q < 4; q++) {
            int l = l0 + j + q;
            float dtv = ((const float*)&dt4)[q];
            float xcv = bf2f(((const ushort*)&xcu)[q]);
            float4 B4 = *(const float4*)(dblp + (size_t)l * 64 + DTR_ + nb);
            float4 C4 = *(const float4*)(dblp + (size_t)l * 64 + DTR_ + N_ + nb);
            float dx = dtv * xcv;
            float a0 = fexp2(dtv * A0), a1 = fexp2(dtv * A1),
                  a2 = fexp2(dtv * A2), a3 = fexp2(dtv * A3);
            h0 = fmaf(a0, h0, dx * B4.x); h1 = fmaf(a1, h1, dx * B4.y);
            h2 = fmaf(a2, h2, dx * B4.z); h3 = fmaf(a3, h3, dx * B4.w);
            float p = h0 * C4.x;
            p = fmaf(h1, C4.y, p); p = fmaf(h2, C4.z, p); p = fmaf(h3, C4.w, p);
            p += __shfl_xor(p, 2); p += __shfl_xor(p, 4);
            if (ng == 0) sY[dloc][c][j + q] = fmaf(xcv, Dd, p);
        }
    }
    __syncthreads();
    // coalesced write: 2 d-rows x 1024 l
    float* yp = y2 + ((size_t)dir * DI_ + (size_t)dgrp * 2) * BL + (size_t)b * L_;
    int lw = tid * 4;
    int cw = tid >> 3, jw = lw & 31;
#pragma unroll
    for (int dd = 0; dd < 2; dd++)
        *(float4*)(yp + (size_t)dd * BL + lw) = *(float4*)&sY[dd][cw][jw];
}

// ---------------- combine + transpose: ycomb_b[bl][d] = (y2_f+y2_b)[d][bl] * silu(z) ----------------
__global__ __launch_bounds__(256) void combine_kernel(
    const float* __restrict__ y2, const float* __restrict__ xz,
    bf16* __restrict__ yc)
{
    __shared__ float tile[32][33];
    int d0 = blockIdx.x * 32, bl0 = blockIdx.y * 32;
    int tx = threadIdx.x & 31, ty = threadIdx.x >> 5;
#pragma unroll
    for (int r = 0; r < 4; r++) {
        int d = d0 + ty * 4 + r;
        tile[ty * 4 + r][tx] = y2[(size_t)d * BL + bl0 + tx]
                             + y2[(size_t)(DI_ + d) * BL + bl0 + tx];
    }
    __syncthreads();
#pragma unroll
    for (int r = 0; r < 4; r++) {
        int bl = bl0 + ty * 4 + r;
        float z = xz[(size_t)bl * (2 * DI_) + DI_ + d0 + tx];
        yc[(size_t)bl * DI_ + d0 + tx] = __float2bfloat16(tile[tx][ty * 4 + r] * siluf(z));
    }
}

extern "C" void kernel_launch(void* const* d_in, const int* in_sizes, int n_in,
                              void* d_out, int out_size, void* d_ws, size_t ws_size,
                              hipStream_t stream) {
    const float* x     = (const float*)d_in[0];
    const float* mask  = (const float*)d_in[1];
    const float* n1w   = (const float*)d_in[2];
    const float* n1b   = (const float*)d_in[3];
    const float* n2w   = (const float*)d_in[4];
    const float* n2b   = (const float*)d_in[5];
    const float* ff1w  = (const float*)d_in[6];
    const float* ff1b  = (const float*)d_in[7];
    const float* ff2w  = (const float*)d_in[8];
    const float* ff2b  = (const float*)d_in[9];
    const float* inpw  = (const float*)d_in[10];
    const float* convw = (const float*)d_in[11];
    const float* convb = (const float*)d_in[12];
    const float* xpw   = (const float*)d_in[13];
    const float* dtpw  = (const float*)d_in[14];
    const float *A_log, *Dp, *outpw, *dtpb;
    if (in_sizes[15] == DI_ * N_) {
        A_log = (const float*)d_in[15]; Dp = (const float*)d_in[16];
        outpw = (const float*)d_in[17]; dtpb = (const float*)d_in[18];
    } else {
        dtpb = (const float*)d_in[15]; A_log = (const float*)d_in[16];
        Dp = (const float*)d_in[17]; outpw = (const float*)d_in[18];
    }

    float* ws = (float*)d_ws;
    bf16*  wb      = (bf16*)ws;                         // 1884160 fu
    float* xz      = ws + 1884160;                      // 4194304 fu (also P9/P12)
    bf16*  xn_b    = (bf16*)(ws + 6078464);             // 524288 fu (also mon_b)
    bf16*  xc_b    = (bf16*)(ws + 6602752);             // 2097152 fu (also h_b)
    float* y2      = ws + 8699904;                      // 4194304 fu  [2][DI][BL]
    float* dblb    = ws + 12894208;                     // 262144 fu
    bf16*  dbl_b   = (bf16*)(ws + 13156352);            // 131072 fu
    float* dtT     = ws + 13287424;                     // 4194304 fu (also P5)
    bf16*  xcT_b   = (bf16*)(ws + 17481728);            // 2097152 fu [2][DI][BL] bf16
    bf16*  ycomb_b = (bf16*)(ws + 19578880);            // 524288 fu

    bf16* inpw_b = wb;
    bf16* xpw_b  = wb + 1048576;
    bf16* dtpw_b = wb + 1114112;
    bf16* outpw_b= wb + 1146880;
    bf16* ff1w_b = wb + 1671168;
    bf16* ff2w_b = wb + 2719744;
    bf16* mon_b  = xn_b;
    bf16* h_b    = xc_b;
    float* P5    = dtT;
    float* P9    = xz;
    float* P12   = xz;

    // 0+1. fused: cast weights to bf16 (3680 blocks) + LN1 (512 blocks)
    prep_kernel<<<dim3(4192), 256, 0, stream>>>(inpw, xpw, dtpw, outpw, ff1w, ff2w, wb,
                                                x, n1w, n1b, xn_b);
    // 2. xz = xn @ in_proj_w^T (2048x2048x512), grid 1024
    mgemm_k<0, 64, 1><<<dim3(32, 32), 256, 0, stream>>>(
        (const short*)xn_b, DM_, (const short*)inpw_b, DM_, xz, nullptr,
        nullptr, 0, 0, BL, 2 * DI_, DM_);
    // 3. conv + silu -> xc_b [bl][d] AND xcT_b [d][bl]
    conv_silu_kernel<<<dim3(512), 256, 0, stream>>>(xz, convw, convb, xc_b, xcT_b);
    // 4. dbl = xc @ x_proj_w^T (4096x64x1024), split-K 8, grid 512
    mgemm_k<0, 64, 8><<<dim3(1, 64, 8), 256, 0, stream>>>(
        (const short*)xc_b, DI_, (const short*)xpw_b, DI_, P5, nullptr,
        nullptr, 0, 0, 2 * BL, 64, DI_);
    reduce_k<8, 0><<<dim3(256), 256, 0, stream>>>(P5, dblb, dbl_b, nullptr, nullptr,
                                                  2 * BL * 64, 64);
    // 5. dtT = softplus(dt_proj_w @ dt_r^T + b[m]) -> f32 [2][DI][BL], one launch
    mgemm_k<4, 32, 1><<<dim3(32, 16, 2), 256, 0, stream>>>(
        (const short*)dtpw_b, DTR_, (const short*)dbl_b, 64,
        dtT, nullptr, dtpb,
        (size_t)BL * 64, (size_t)DI_ * BL, DI_, BL, DTR_);
    // 6. chunked scan (both dirs, 2048 blocks) -> y2[2][DI][BL]
    scan_kernel<<<dim3(DI_ / 2, B_, 2), 256, 0, stream>>>(dtT, xcT_b, dblb, A_log, Dp, y2);
    // 7. ycomb_b = (y2_f + y2_b)^T * silu(z) -> bf16
    combine_kernel<<<dim3(DI_ / 32, BL / 32), 256, 0, stream>>>(y2, xz, ycomb_b);
    // 8. mo_raw partials = ycomb @ out_proj_w^T (2048x512x1024), split-K 2, grid 512
    mgemm_k<0, 64, 2><<<dim3(8, 32, 2), 256, 0, stream>>>(
        (const short*)ycomb_b, DI_, (const short*)outpw_b, DI_, P9, nullptr,
        nullptr, 0, 0, BL, DM_, DI_);
    // 9. mo_n = LN((P9_0 + P9_1) * mask) -> bf16  (fused reduce + LN)
    ln2r_kernel<<<dim3(BL / 4), 256, 0, stream>>>(P9, n2w, n2b, mask, mon_b);
    // 10. h = selu(mo_n @ ff1_w^T + b) -> bf16 (2048x2048x512), grid 1024
    mgemm_k<2, 64, 1><<<dim3(32, 32), 256, 0, stream>>>(
        (const short*)mon_b, DM_, (const short*)ff1w_b, DM_, nullptr, h_b,
        ff1b, 0, 0, BL, 4 * DM_, DM_);
    // 11. out = h @ ff2_w^T (2048x512x2048), split-K 2, grid 512; reduce adds bias + x
    mgemm_k<0, 64, 2><<<dim3(8, 32, 2), 256, 0, stream>>>(
        (const short*)h_b, 4 * DM_, (const short*)ff2w_b, 4 * DM_, P12, nullptr,
        nullptr, 0, 0, BL, DM_, 4 * DM_);
    reduce_k<2, 1><<<dim3(1024), 256, 0, stream>>>(P12, (float*)d_out, nullptr, ff2b, x,
                                                   BL * DM_, DM_);
}

// Round 17
// 160.927 us; speedup vs baseline: 1.1899x; 1.1444x over previous
//
#include <hip/hip_runtime.h>
#include <hip/hip_bf16.h>

typedef __hip_bfloat16 bf16;

#define B_   2
#define L_   1024
#define DM_  512
#define DI_  1024
#define N_   16
#define K_   12
#define DTR_ 32

static constexpr int BLD  = B_ * L_ * DI_;   // 2097152
static constexpr int BL   = B_ * L_;         // 2048

using bf16x8 = __attribute__((ext_vector_type(8))) short;
using f32x4  = __attribute__((ext_vector_type(4))) float;
using u16x8  = __attribute__((ext_vector_type(8))) unsigned short;

__device__ __forceinline__ float siluf(float x) { return x / (1.f + __expf(-x)); }
__device__ __forceinline__ float softplusf(float x) {
    return fmaxf(x, 0.f) + log1pf(expf(-fabsf(x)));
}
__device__ __forceinline__ float seluf(float x) {
    const float lam = 1.0507009873554805f, alp = 1.6732632423543772f;
    return x > 0.f ? lam * x : lam * alp * (expf(x) - 1.f);
}
__device__ __forceinline__ ushort bfbits(float x) {
    bf16 v = __float2bfloat16(x);
    return *(ushort*)&v;
}
__device__ __forceinline__ float bf2f(ushort u) {
    return __uint_as_float(((unsigned)u) << 16);
}
// native hardware exp2 (single v_exp_f32); fallback keeps correctness
__device__ __forceinline__ float fexp2(float x) {
#if __has_builtin(__builtin_amdgcn_exp2f)
    return __builtin_amdgcn_exp2f(x);
#else
    return __expf(x * 0.6931471805599453f);
#endif
}
// async global -> LDS, 16B per lane; LDS dest = uniform base + lane*16
__device__ __forceinline__ void gload16(const void* g, void* l) {
    __builtin_amdgcn_global_load_lds(
        (const __attribute__((address_space(1))) void*)g,
        (__attribute__((address_space(3))) void*)l, 16, 0, 0);
}

// ---------------- fused prep: weight cast f32->bf16 (blocks 0..3679) + LN1 (blocks 3680..4191) ----------------
__global__ __launch_bounds__(256) void prep_kernel(
    const float* __restrict__ s0, const float* __restrict__ s1, const float* __restrict__ s2,
    const float* __restrict__ s3, const float* __restrict__ s4, const float* __restrict__ s5,
    bf16* __restrict__ dst,
    const float* __restrict__ x, const float* __restrict__ n1w, const float* __restrict__ n1b,
    bf16* __restrict__ xn)
{
    if (blockIdx.x < 3680) {
        int i = blockIdx.x * 256 + threadIdx.x;   // total 942080 vec4
        const float* src; int off;
        if (i < 262144)      { src = s0; off = i; }
        else if (i < 278528) { src = s1; off = i - 262144; }
        else if (i < 286720) { src = s2; off = i - 278528; }
        else if (i < 417792) { src = s3; off = i - 286720; }
        else if (i < 679936) { src = s4; off = i - 417792; }
        else                 { src = s5; off = i - 679936; }
        float4 v = ((const float4*)src)[off];
        bf16* d = dst + (size_t)i * 4;
        d[0] = __float2bfloat16(v.x); d[1] = __float2bfloat16(v.y);
        d[2] = __float2bfloat16(v.z); d[3] = __float2bfloat16(v.w);
    } else {
        int row  = (blockIdx.x - 3680) * 4 + (threadIdx.x >> 6);
        int lane = threadIdx.x & 63;
        const float* xr = x + (size_t)row * DM_;
        float v[8];
        float s = 0.f, ss = 0.f;
#pragma unroll
        for (int i = 0; i < 8; i++) {
            v[i] = xr[lane + i * 64];
            s += v[i]; ss += v[i] * v[i];
        }
#pragma unroll
        for (int o = 32; o >= 1; o >>= 1) { s += __shfl_xor(s, o); ss += __shfl_xor(ss, o); }
        float mean = s * (1.f / DM_);
        float var  = ss * (1.f / DM_) - mean * mean;
        float r    = rsqrtf(var + 1e-5f);
        bf16* yr = xn + (size_t)row * DM_;
#pragma unroll
        for (int i = 0; i < 8; i++) {
            int c = lane + i * 64;
            yr[c] = __float2bfloat16((v[i] - mean) * r * n1w[c] + n1b[c]);
        }
    }
}

// ---------------- fused: (P0+P1) * mask -> LayerNorm -> bf16 (for mo path) ----------------
__global__ __launch_bounds__(256) void ln2r_kernel(
    const float* __restrict__ P, const float* __restrict__ w, const float* __restrict__ b,
    const float* __restrict__ mask, bf16* __restrict__ y)
{
    int row  = blockIdx.x * 4 + (threadIdx.x >> 6);
    int lane = threadIdx.x & 63;
    const float* p0 = P + (size_t)row * DM_;
    const float* p1 = P + (size_t)BL * DM_ + (size_t)row * DM_;
    float mval = mask[row];
    float v[8];
    float s = 0.f, ss = 0.f;
#pragma unroll
    for (int i = 0; i < 8; i++) {
        int c = lane + i * 64;
        v[i] = (p0[c] + p1[c]) * mval;
        s += v[i]; ss += v[i] * v[i];
    }
#pragma unroll
    for (int o = 32; o >= 1; o >>= 1) { s += __shfl_xor(s, o); ss += __shfl_xor(ss, o); }
    float mean = s * (1.f / DM_);
    float var  = ss * (1.f / DM_) - mean * mean;
    float r    = rsqrtf(var + 1e-5f);
    bf16* yr = y + (size_t)row * DM_;
#pragma unroll
    for (int i = 0; i < 8; i++) {
        int c = lane + i * 64;
        yr[c] = __float2bfloat16((v[i] - mean) * r * w[c] + b[c]);
    }
}

// ---------------- MFMA GEMM: C(M,N) = A(M,K) @ W(N,K)^T  (bf16 in, fp32 acc) ----------------
// global_load_lds staging (16B/lane, linear LDS); BK=64 uses XOR col-swizzle (source+read)
// to keep ds_read_b128 at the 8-cycle bank floor. BK=32 is naturally conflict-optimal.
// KS>1: write fp32 partials at C + z*M*N. KS==1 MODE: 0 plain  1 bias[n]+softplus
// 2 bias[n]+selu  4 bias[m]+softplus. zoffW/zoffC: per-blockIdx.z operand offsets.
template<int MODE, int BK, int KS>
__global__ __launch_bounds__(256) void mgemm_k(
    const short* __restrict__ A, int lda,
    const short* __restrict__ W, int ldw,
    float* __restrict__ C, bf16* __restrict__ Cb,
    const float* __restrict__ bias,
    size_t zoffW, size_t zoffC,
    int M, int N, int Kd)
{
    constexpr int UPR   = BK / 8;        // 16B units per row
    constexpr int RPC   = 64 / UPR;      // rows covered per gload call (64 lanes)
    constexpr int CALLS = BK / 32;       // gload calls per operand per wave-row-block
    __shared__ __align__(16) short As[64 * BK];
    __shared__ __align__(16) short Ws[64 * BK];
    W += (size_t)blockIdx.z * zoffW;
    if (C)  C  += (size_t)blockIdx.z * zoffC;
    if (Cb) Cb += (size_t)blockIdx.z * zoffC;
    int bm = blockIdx.y * 64, bn = blockIdx.x * 64;
    int tid = threadIdx.x;
    int lane = tid & 63, w = tid >> 6;
    int wm = (w >> 1) * 32, wn = (w & 1) * 32;
    int l15 = lane & 15, l4 = lane >> 4;
    f32x4 acc[2][2] = {};
    int kbeg = (KS > 1) ? blockIdx.z * (Kd / KS) : 0;
    int kend = (KS > 1) ? kbeg + Kd / KS : Kd;
    // per-call staging geometry
    int rowc[CALLS], colc[CALLS], basec[CALLS];
#pragma unroll
    for (int k = 0; k < CALLS; k++) {
        int r  = w * 16 + k * RPC + (lane / UPR);
        int u  = lane & (UPR - 1);
        int sw = (BK == 64) ? (r & 7) : 0;
        rowc[k]  = r;
        colc[k]  = (u ^ sw) * 8;
        basec[k] = (w * 16 + k * RPC) * BK;
    }
    for (int k0 = kbeg; k0 < kend; k0 += BK) {
#pragma unroll
        for (int k = 0; k < CALLS; k++) {
            gload16(A + (size_t)(bm + rowc[k]) * lda + k0 + colc[k], &As[basec[k]]);
            gload16(W + (size_t)(bn + rowc[k]) * ldw + k0 + colc[k], &Ws[basec[k]]);
        }
        __syncthreads();
#pragma unroll
        for (int ks = 0; ks < BK / 32; ks++) {
            bf16x8 af[2], bfr[2];
#pragma unroll
            for (int mi = 0; mi < 2; mi++) {
                int r  = wm + mi * 16 + l15;
                int cu = ((ks * 4 + l4) ^ ((BK == 64) ? (r & 7) : 0)) * 8;
                af[mi] = *(const bf16x8*)&As[r * BK + cu];
            }
#pragma unroll
            for (int ni = 0; ni < 2; ni++) {
                int r  = wn + ni * 16 + l15;
                int cu = ((ks * 4 + l4) ^ ((BK == 64) ? (r & 7) : 0)) * 8;
                bfr[ni] = *(const bf16x8*)&Ws[r * BK + cu];
            }
#pragma unroll
            for (int mi = 0; mi < 2; mi++)
#pragma unroll
                for (int ni = 0; ni < 2; ni++)
                    acc[mi][ni] = __builtin_amdgcn_mfma_f32_16x16x32_bf16(af[mi], bfr[ni], acc[mi][ni], 0, 0, 0);
        }
        __syncthreads();
    }
    if (KS > 1) {
        float* P = C + (size_t)blockIdx.z * M * N;
#pragma unroll
        for (int mi = 0; mi < 2; mi++) {
            int row0 = bm + wm + mi * 16 + l4 * 4;
#pragma unroll
            for (int ni = 0; ni < 2; ni++) {
                int col = bn + wn + ni * 16 + l15;
#pragma unroll
                for (int j = 0; j < 4; j++)
                    P[(size_t)(row0 + j) * N + col] = acc[mi][ni][j];
            }
        }
    } else {
#pragma unroll
        for (int mi = 0; mi < 2; mi++) {
            int row0 = bm + wm + mi * 16 + l4 * 4;
#pragma unroll
            for (int ni = 0; ni < 2; ni++) {
                int col = bn + wn + ni * 16 + l15;
#pragma unroll
                for (int j = 0; j < 4; j++) {
                    int row = row0 + j;
                    float v = acc[mi][ni][j];
                    if (MODE == 1) v = softplusf(v + bias[col]);
                    if (MODE == 2) v = seluf(v + bias[col]);
                    if (MODE == 4) v = softplusf(v + bias[row]);
                    if (C)  C[(size_t)row * N + col] = v;
                    if (Cb) Cb[(size_t)row * N + col] = __float2bfloat16(v);
                }
            }
        }
    }
}

// ---------------- split-K reduce: sum KS partial slices (+ optional bias/resid) ----------------
template<int KS, int RMODE>
__global__ __launch_bounds__(256) void reduce_k(
    const float* __restrict__ P, float* __restrict__ C, bf16* __restrict__ Cb,
    const float* __restrict__ bias, const float* __restrict__ resid,
    int MN, int N)
{
    int i = (blockIdx.x * 256 + threadIdx.x) * 4;
    float4 v = *(const float4*)(P + i);
#pragma unroll
    for (int s = 1; s < KS; s++) {
        float4 u = *(const float4*)(P + (size_t)s * MN + i);
        v.x += u.x; v.y += u.y; v.z += u.z; v.w += u.w;
    }
    if (RMODE == 1) {
        float4 bz = *(const float4*)(bias + (i % N));
        float4 rx = *(const float4*)(resid + i);
        v.x += bz.x + rx.x; v.y += bz.y + rx.y;
        v.z += bz.z + rx.z; v.w += bz.w + rx.w;
    }
    if (C) *(float4*)(C + i) = v;
    if (Cb) {
        bf16* d = Cb + i;
        d[0] = __float2bfloat16(v.x); d[1] = __float2bfloat16(v.y);
        d[2] = __float2bfloat16(v.z); d[3] = __float2bfloat16(v.w);
    }
}

// ---------------- depthwise conv + SiLU: 4 ch x 8 pos / thread, dual output (row + transposed) ----------------
__global__ __launch_bounds__(256) void conv_silu_kernel(
    const float* __restrict__ xz, const float* __restrict__ cw,
    const float* __restrict__ cb, bf16* __restrict__ xcb, bf16* __restrict__ xcbT)
{
    int gid = blockIdx.x * 256 + threadIdx.x;     // 131072 total
    int d4  = (gid & 255) * 4;
    int l0  = ((gid >> 8) & 127) * 8;
    int b   = (gid >> 15) & 1;
    int dir = gid >> 16;
    float wv[4][12];
    {
        const float4* cwp = (const float4*)(cw + d4 * 12);
        float buf[48];
#pragma unroll
        for (int i = 0; i < 12; i++) {
            float4 t = cwp[i];
            buf[4*i] = t.x; buf[4*i+1] = t.y; buf[4*i+2] = t.z; buf[4*i+3] = t.w;
        }
#pragma unroll
        for (int dd = 0; dd < 4; dd++)
#pragma unroll
            for (int k = 0; k < 12; k++) wv[dd][k] = buf[dd * 12 + k];
    }
    float4 cb4 = *(const float4*)(cb + d4);
    float4 tap[19];
    int tbase = (dir == 0) ? (l0 - (K_ - 1)) : l0;
#pragma unroll
    for (int i = 0; i < 19; i++) {
        int ls = tbase + i;
        if (ls >= 0 && ls < L_)
            tap[i] = *(const float4*)(xz + ((size_t)(b * L_ + ls)) * (2 * DI_) + d4);
        else
            tap[i] = make_float4(0.f, 0.f, 0.f, 0.f);
    }
    ushort ot[4][8];
#pragma unroll
    for (int j = 0; j < 8; j++) {
        float a0 = cb4.x, a1 = cb4.y, a2 = cb4.z, a3 = cb4.w;
        if (dir == 0) {
#pragma unroll
            for (int k = 0; k < K_; k++) {
                float4 t = tap[j + k];
                a0 = fmaf(wv[0][k], t.x, a0); a1 = fmaf(wv[1][k], t.y, a1);
                a2 = fmaf(wv[2][k], t.z, a2); a3 = fmaf(wv[3][k], t.w, a3);
            }
        } else {
#pragma unroll
            for (int k = 0; k < K_; k++) {
                float4 t = tap[j + (K_ - 1) - k];
                a0 = fmaf(wv[0][k], t.x, a0); a1 = fmaf(wv[1][k], t.y, a1);
                a2 = fmaf(wv[2][k], t.z, a2); a3 = fmaf(wv[3][k], t.w, a3);
            }
        }
        ot[0][j] = bfbits(siluf(a0)); ot[1][j] = bfbits(siluf(a1));
        ot[2][j] = bfbits(siluf(a2)); ot[3][j] = bfbits(siluf(a3));
    }
    // row-major store [bl][d]
    size_t obase = (size_t)dir * BLD + ((size_t)(b * L_ + l0)) * DI_ + d4;
#pragma unroll
    for (int j = 0; j < 8; j++) {
        ushort4 o; o.x = ot[0][j]; o.y = ot[1][j]; o.z = ot[2][j]; o.w = ot[3][j];
        *(ushort4*)(xcb + obase + (size_t)j * DI_) = o;
    }
    // transposed store [d][bl]
#pragma unroll
    for (int dd = 0; dd < 4; dd++) {
        u16x8 v;
#pragma unroll
        for (int j = 0; j < 8; j++) v[j] = ot[dd][j];
        *(u16x8*)(xcbT + ((size_t)dir * DI_ + d4 + dd) * BL + (size_t)b * L_ + l0) = v;
    }
}

// ---------------- chunked selective scan: 32 chunks x 32 steps, 4 n / lane ----------------
// block 256 thr = 32 chunks x 4 ngrp x 2 dloc; grid (DI/2, B, 2 dirs) = 2048 blocks
// A pre-scaled by log2(e): a = exp2(dt * A') -> single native v_exp_f32
__global__ __launch_bounds__(256, 8) void scan_kernel(
    const float* __restrict__ dtT,   // [2][DI][BL] f32
    const bf16*  __restrict__ xcT,   // [2][DI][BL] bf16
    const float* __restrict__ dbl,   // [2][BL][64] f32
    const float* __restrict__ A_log, const float* __restrict__ Dp,
    float* __restrict__ y2)          // [2][DI][BL] f32
{
    __shared__ float sA[32][2][17];
    __shared__ float sB[32][2][17];
    __shared__ float sY[2][32][36];
    int dgrp = blockIdx.x, b = blockIdx.y, dir = blockIdx.z;
    int tid = threadIdx.x;
    int dloc = tid & 1, ng = (tid >> 1) & 3, c = tid >> 3;
    int d = dgrp * 2 + dloc;
    size_t rowbase = ((size_t)dir * DI_ + d) * BL + (size_t)b * L_;
    const float* dtp = dtT + rowbase;
    const bf16*  xcp = xcT + rowbase;
    const float* dblp = dbl + ((size_t)dir * BL + (size_t)b * L_) * 64;
    int nb = ng * 4;
    const float LOG2E = 1.44269504088896f;
    float A0 = -__expf(A_log[d * N_ + nb + 0]) * LOG2E;
    float A1 = -__expf(A_log[d * N_ + nb + 1]) * LOG2E;
    float A2 = -__expf(A_log[d * N_ + nb + 2]) * LOG2E;
    float A3 = -__expf(A_log[d * N_ + nb + 3]) * LOG2E;
    float Dd = Dp[d];
    int l0 = c * 32;
    // pass 1: local scan -> chunk summaries
    float ac0=1.f, ac1=1.f, ac2=1.f, ac3=1.f;
    float h0=0.f, h1=0.f, h2=0.f, h3=0.f;
    for (int j = 0; j < 32; j += 4) {
        float4 dt4 = *(const float4*)(dtp + l0 + j);
        ushort4 xcu = *(const ushort4*)(xcp + l0 + j);
#pragma unroll
        for (int q = 0; q < 4; q++) {
            int l = l0 + j + q;
            float dtv = ((const float*)&dt4)[q];
            float xcv = bf2f(((const ushort*)&xcu)[q]);
            float4 B4 = *(const float4*)(dblp + (size_t)l * 64 + DTR_ + nb);
            float dx = dtv * xcv;
            float a0 = fexp2(dtv * A0), a1 = fexp2(dtv * A1),
                  a2 = fexp2(dtv * A2), a3 = fexp2(dtv * A3);
            ac0 *= a0; ac1 *= a1; ac2 *= a2; ac3 *= a3;
            h0 = fmaf(a0, h0, dx * B4.x); h1 = fmaf(a1, h1, dx * B4.y);
            h2 = fmaf(a2, h2, dx * B4.z); h3 = fmaf(a3, h3, dx * B4.w);
        }
    }
    sA[c][dloc][nb+0]=ac0; sA[c][dloc][nb+1]=ac1; sA[c][dloc][nb+2]=ac2; sA[c][dloc][nb+3]=ac3;
    sB[c][dloc][nb+0]=h0;  sB[c][dloc][nb+1]=h1;  sB[c][dloc][nb+2]=h2;  sB[c][dloc][nb+3]=h3;
    __syncthreads();
    // exclusive cross-chunk prefix (<=31 steps)
    float p0=0.f, p1=0.f, p2=0.f, p3=0.f;
    for (int cc = 0; cc < c; cc++) {
        p0 = fmaf(sA[cc][dloc][nb+0], p0, sB[cc][dloc][nb+0]);
        p1 = fmaf(sA[cc][dloc][nb+1], p1, sB[cc][dloc][nb+1]);
        p2 = fmaf(sA[cc][dloc][nb+2], p2, sB[cc][dloc][nb+2]);
        p3 = fmaf(sA[cc][dloc][nb+3], p3, sB[cc][dloc][nb+3]);
    }
    h0 = p0; h1 = p1; h2 = p2; h3 = p3;
    // pass 2: rescan + n-reduce (in-reg 4 + shfl over ng bits 1..2)
    for (int j = 0; j < 32; j += 4) {
        float4 dt4 = *(const float4*)(dtp + l0 + j);
        ushort4 xcu = *(const ushort4*)(xcp + l0 + j);
#pragma unroll
        for (int q = 0; q < 4; q++) {
            int l = l0 + j + q;
            float dtv = ((const float*)&dt4)[q];
            float xcv = bf2f(((const ushort*)&xcu)[q]);
            float4 B4 = *(const float4*)(dblp + (size_t)l * 64 + DTR_ + nb);
            float4 C4 = *(const float4*)(dblp + (size_t)l * 64 + DTR_ + N_ + nb);
            float dx = dtv * xcv;
            float a0 = fexp2(dtv * A0), a1 = fexp2(dtv * A1),
                  a2 = fexp2(dtv * A2), a3 = fexp2(dtv * A3);
            h0 = fmaf(a0, h0, dx * B4.x); h1 = fmaf(a1, h1, dx * B4.y);
            h2 = fmaf(a2, h2, dx * B4.z); h3 = fmaf(a3, h3, dx * B4.w);
            float p = h0 * C4.x;
            p = fmaf(h1, C4.y, p); p = fmaf(h2, C4.z, p); p = fmaf(h3, C4.w, p);
            p += __shfl_xor(p, 2); p += __shfl_xor(p, 4);
            if (ng == 0) sY[dloc][c][j + q] = fmaf(xcv, Dd, p);
        }
    }
    __syncthreads();
    // coalesced write: 2 d-rows x 1024 l
    float* yp = y2 + ((size_t)dir * DI_ + (size_t)dgrp * 2) * BL + (size_t)b * L_;
    int lw = tid * 4;
    int cw = tid >> 3, jw = lw & 31;
#pragma unroll
    for (int dd = 0; dd < 2; dd++)
        *(float4*)(yp + (size_t)dd * BL + lw) = *(float4*)&sY[dd][cw][jw];
}

// ---------------- combine + transpose: ycomb_b[bl][d] = (y2_f+y2_b)[d][bl] * silu(z) ----------------
__global__ __launch_bounds__(256) void combine_kernel(
    const float* __restrict__ y2, const float* __restrict__ xz,
    bf16* __restrict__ yc)
{
    __shared__ float tile[32][33];
    int d0 = blockIdx.x * 32, bl0 = blockIdx.y * 32;
    int tx = threadIdx.x & 31, ty = threadIdx.x >> 5;
#pragma unroll
    for (int r = 0; r < 4; r++) {
        int d = d0 + ty * 4 + r;
        tile[ty * 4 + r][tx] = y2[(size_t)d * BL + bl0 + tx]
                             + y2[(size_t)(DI_ + d) * BL + bl0 + tx];
    }
    __syncthreads();
#pragma unroll
    for (int r = 0; r < 4; r++) {
        int bl = bl0 + ty * 4 + r;
        float z = xz[(size_t)bl * (2 * DI_) + DI_ + d0 + tx];
        yc[(size_t)bl * DI_ + d0 + tx] = __float2bfloat16(tile[tx][ty * 4 + r] * siluf(z));
    }
}

extern "C" void kernel_launch(void* const* d_in, const int* in_sizes, int n_in,
                              void* d_out, int out_size, void* d_ws, size_t ws_size,
                              hipStream_t stream) {
    const float* x     = (const float*)d_in[0];
    const float* mask  = (const float*)d_in[1];
    const float* n1w   = (const float*)d_in[2];
    const float* n1b   = (const float*)d_in[3];
    const float* n2w   = (const float*)d_in[4];
    const float* n2b   = (const float*)d_in[5];
    const float* ff1w  = (const float*)d_in[6];
    const float* ff1b  = (const float*)d_in[7];
    const float* ff2w  = (const float*)d_in[8];
    const float* ff2b  = (const float*)d_in[9];
    const float* inpw  = (const float*)d_in[10];
    const float* convw = (const float*)d_in[11];
    const float* convb = (const float*)d_in[12];
    const float* xpw   = (const float*)d_in[13];
    const float* dtpw  = (const float*)d_in[14];
    const float *A_log, *Dp, *outpw, *dtpb;
    if (in_sizes[15] == DI_ * N_) {
        A_log = (const float*)d_in[15]; Dp = (const float*)d_in[16];
        outpw = (const float*)d_in[17]; dtpb = (const float*)d_in[18];
    } else {
        dtpb = (const float*)d_in[15]; A_log = (const float*)d_in[16];
        Dp = (const float*)d_in[17]; outpw = (const float*)d_in[18];
    }

    float* ws = (float*)d_ws;
    bf16*  wb      = (bf16*)ws;                         // 1884160 fu
    float* xz      = ws + 1884160;                      // 4194304 fu (also P9/P12)
    bf16*  xn_b    = (bf16*)(ws + 6078464);             // 524288 fu (also mon_b)
    bf16*  xc_b    = (bf16*)(ws + 6602752);             // 2097152 fu (also h_b)
    float* y2      = ws + 8699904;                      // 4194304 fu  [2][DI][BL]
    float* dblb    = ws + 12894208;                     // 262144 fu
    bf16*  dbl_b   = (bf16*)(ws + 13156352);            // 131072 fu
    float* dtT     = ws + 13287424;                     // 4194304 fu (also P5)
    bf16*  xcT_b   = (bf16*)(ws + 17481728);            // 2097152 fu [2][DI][BL] bf16
    bf16*  ycomb_b = (bf16*)(ws + 19578880);            // 524288 fu

    bf16* inpw_b = wb;
    bf16* xpw_b  = wb + 1048576;
    bf16* dtpw_b = wb + 1114112;
    bf16* outpw_b= wb + 1146880;
    bf16* ff1w_b = wb + 1671168;
    bf16* ff2w_b = wb + 2719744;
    bf16* mon_b  = xn_b;
    bf16* h_b    = xc_b;
    float* P5    = dtT;
    float* P9    = xz;
    float* P12   = xz;

    // 0+1. fused: cast weights to bf16 (3680 blocks) + LN1 (512 blocks)
    prep_kernel<<<dim3(4192), 256, 0, stream>>>(inpw, xpw, dtpw, outpw, ff1w, ff2w, wb,
                                                x, n1w, n1b, xn_b);
    // 2. xz = xn @ in_proj_w^T (2048x2048x512), grid 1024
    mgemm_k<0, 64, 1><<<dim3(32, 32), 256, 0, stream>>>(
        (const short*)xn_b, DM_, (const short*)inpw_b, DM_, xz, nullptr,
        nullptr, 0, 0, BL, 2 * DI_, DM_);
    // 3. conv + silu -> xc_b [bl][d] AND xcT_b [d][bl]
    conv_silu_kernel<<<dim3(512), 256, 0, stream>>>(xz, convw, convb, xc_b, xcT_b);
    // 4. dbl = xc @ x_proj_w^T (4096x64x1024), split-K 8, grid 512
    mgemm_k<0, 64, 8><<<dim3(1, 64, 8), 256, 0, stream>>>(
        (const short*)xc_b, DI_, (const short*)xpw_b, DI_, P5, nullptr,
        nullptr, 0, 0, 2 * BL, 64, DI_);
    reduce_k<8, 0><<<dim3(256), 256, 0, stream>>>(P5, dblb, dbl_b, nullptr, nullptr,
                                                  2 * BL * 64, 64);
    // 5. dtT = softplus(dt_proj_w @ dt_r^T + b[m]) -> f32 [2][DI][BL], one launch
    mgemm_k<4, 32, 1><<<dim3(32, 16, 2), 256, 0, stream>>>(
        (const short*)dtpw_b, DTR_, (const short*)dbl_b, 64,
        dtT, nullptr, dtpb,
        (size_t)BL * 64, (size_t)DI_ * BL, DI_, BL, DTR_);
    // 6. chunked scan (both dirs, 2048 blocks) -> y2[2][DI][BL]
    scan_kernel<<<dim3(DI_ / 2, B_, 2), 256, 0, stream>>>(dtT, xcT_b, dblb, A_log, Dp, y2);
    // 7. ycomb_b = (y2_f + y2_b)^T * silu(z) -> bf16
    combine_kernel<<<dim3(DI_ / 32, BL / 32), 256, 0, stream>>>(y2, xz, ycomb_b);
    // 8. mo_raw partials = ycomb @ out_proj_w^T (2048x512x1024), split-K 2, grid 512
    mgemm_k<0, 64, 2><<<dim3(8, 32, 2), 256, 0, stream>>>(
        (const short*)ycomb_b, DI_, (const short*)outpw_b, DI_, P9, nullptr,
        nullptr, 0, 0, BL, DM_, DI_);
    // 9. mo_n = LN((P9_0 + P9_1) * mask) -> bf16  (fused reduce + LN)
    ln2r_kernel<<<dim3(BL / 4), 256, 0, stream>>>(P9, n2w, n2b, mask, mon_b);
    // 10. h = selu(mo_n @ ff1_w^T + b) -> bf16 (2048x2048x512), grid 1024
    mgemm_k<2, 64, 1><<<dim3(32, 32), 256, 0, stream>>>(
        (const short*)mon_b, DM_, (const short*)ff1w_b, DM_, nullptr, h_b,
        ff1b, 0, 0, BL, 4 * DM_, DM_);
    // 11. out = h @ ff2_w^T (2048x512x2048), split-K 2, grid 512; reduce adds bias + x
    mgemm_k<0, 64, 2><<<dim3(8, 32, 2), 256, 0, stream>>>(
        (const short*)h_b, 4 * DM_, (const short*)ff2w_b, 4 * DM_, P12, nullptr,
        nullptr, 0, 0, BL, DM_, 4 * DM_);
    reduce_k<2, 1><<<dim3(1024), 256, 0, stream>>>(P12, (float*)d_out, nullptr, ff2b, x,
                                                   BL * DM_, DM_);
}